// Round 8
// baseline (133.734 us; speedup 1.0000x reference)
//
#include <hip/hip_runtime.h>

// LePEAttention without softmax:  out = Q (K^T V) * (2*SCALE)
// q,k,v: (T=4, B=2, C=256, H=56, W=56) fp32. Windows: 2 of 56x28 (N=1568),
// heads=8, d=32. 128 problems: p = ((t*2+b)*2+win)*8+head.
//
// Kernel 1 (kv): Mpart[p][s] = K_s^T V_s over 56-position split s (28 splits).
//   3584 blocks, 16KB LDS -> 8 blocks/CU, 14 generations/CU: the per-block
//   stage(vmcnt drain) hides under 7 co-resident blocks' compute (inter-block
//   TLP -- the R4/R5 intra-block pipeline hit the VGPR cap and spilled).
//   global_load_lds staging, permuted-slot layout (conflict-free b128),
//   pk_fma. Mapping verified end-to-end in R3.
// Kernel 2 (qm): M = SCALE2 * sum_s Mpart[p][s];  out = Q * M.
//   512 blocks (4/problem), 2 positions/thread (float2): halves M-broadcast
//   reads and Q/out transactions per output element vs 1-pos/thread.

#define HW 3136
#define WDIM 56
#define SPLIT 28
#define PSPLIT 56
#define SCALE2 0.35355339059327373f   // 2 * 32^-0.5

typedef const __attribute__((address_space(1))) void gas_void;
typedef __attribute__((address_space(3))) void las_void;
typedef float v2f __attribute__((ext_vector_type(2)));

// ---------------- Kernel 1: partial K^T V ----------------------------------
__global__ __launch_bounds__(256) void kv_kernel(const float* __restrict__ K,
                                                 const float* __restrict__ V,
                                                 float* __restrict__ Mpart) {
    // data: [tensor:2][pq:14][slot:32] 16B-quads = 14336 B; reduce overlay 16 KB
    __shared__ float lds[4096];

    const int blk = blockIdx.x;              // 3584 = 128 * 28
    const int p   = blk / SPLIT;
    const int s   = blk - p * SPLIT;
    const int head = p & 7;
    const int win  = (p >> 3) & 1;
    const int b    = (p >> 4) & 1;
    const int t    = p >> 5;

    const size_t base = (size_t)((t * 2 + b) * 256 + head * 32) * HW;
    const float* __restrict__ Kb = K + base;
    const float* __restrict__ Vb = V + base;

    const int tid = threadIdx.x;
    const int l   = tid & 63;
    const int w   = tid >> 6;

    // ---- stage: 896 16B-quads (2 tensors x 32 slots x 14 pos-quads).
    // Linear LDS dest (wave-uniform base + lane*16); per-lane GLOBAL source
    // realizes the permuted-slot layout. Issue 3 covers quads 768..895
    // (waves 0,1 only -- wave-uniform predicate).
    #pragma unroll
    for (int i = 0; i < 4; ++i) {
        if (i < 3 || w < 2) {
            const int q    = i * 256 + tid;       // quad 0..895
            const int isv  = q >= 448 ? 1 : 0;    // wave-uniform (448 = 7*64)
            const int r    = q - isv * 448;
            const int pq   = r >> 5;              // position quad 0..13
            const int slot = r & 31;              // permuted channel slot
            const int ch   = ((slot & 7) << 2) + (slot >> 3);
            const int n    = s * PSPLIT + pq * 4; // global position, 4-aligned
            const int y    = n / 28;
            const int x    = n - y * 28;
            const float* src = (isv ? Vb : Kb)
                             + (size_t)ch * HW + y * WDIM + win * 28 + x;
            float* dst = &lds[i * 1024 + w * 256];   // wave-uniform
            __builtin_amdgcn_global_load_lds((gas_void*)src, (las_void*)dst, 16, 0, 0);
        }
    }
    __syncthreads();   // compiler emits s_waitcnt vmcnt(0) before barrier

    // ---- rank-1 accumulation: lane owns channels dd=4*gg+i (i=0..3, via
    // granule gg+8i) x de=4*e+jj. Wave w covers pq rows {w, w+4, w+8, w+12<14}.
    const int gg = l >> 3;
    const int e  = l & 7;

    v2f acc2[4][4] = {};
    #pragma unroll
    for (int j = 0; j < 4; ++j) {
        const int pq = w + 4 * j;
        if (pq < 14) {                      // wave-uniform
            const int rowb = pq * 128;      // float offset of this pq row
            float4 ka[4], va[4];
            #pragma unroll
            for (int i = 0; i < 4; ++i) {
                ka[i] = *(const float4*)&lds[rowb + (gg + 8 * i) * 4];
                va[i] = *(const float4*)&lds[1792 + rowb + (e + 8 * i) * 4];
            }
            #pragma unroll
            for (int i = 0; i < 4; ++i) {
                const v2f ka_lo = {ka[i].x, ka[i].y};
                const v2f ka_hi = {ka[i].z, ka[i].w};
                #pragma unroll
                for (int jj = 0; jj < 4; ++jj) {
                    const v2f va_lo = {va[jj].x, va[jj].y};
                    const v2f va_hi = {va[jj].z, va[jj].w};
                    acc2[i][jj] += ka_lo * va_lo;   // v_pk_fma_f32
                    acc2[i][jj] += ka_hi * va_hi;
                }
            }
        }
    }
    __syncthreads();

    // ---- reduce the 4 wave copies (overlay lds[0..4095])
    const int dd0 = gg * 4;
    const int de0 = e * 4;
    #pragma unroll
    for (int i = 0; i < 4; ++i)
        #pragma unroll
        for (int jj = 0; jj < 4; ++jj)
            lds[w * 1024 + (dd0 + i) * 32 + (de0 + jj)] = acc2[i][jj].x + acc2[i][jj].y;
    __syncthreads();

    const float4 r0 = *(const float4*)&lds[tid * 4];
    const float4 r1 = *(const float4*)&lds[1024 + tid * 4];
    const float4 r2 = *(const float4*)&lds[2048 + tid * 4];
    const float4 r3 = *(const float4*)&lds[3072 + tid * 4];
    float4 o;
    o.x = r0.x + r1.x + r2.x + r3.x;
    o.y = r0.y + r1.y + r2.y + r3.y;
    o.z = r0.z + r1.z + r2.z + r3.z;
    o.w = r0.w + r1.w + r2.w + r3.w;
    *(float4*)&Mpart[(size_t)blk * 1024 + tid * 4] = o;
}

// ---------------- Kernel 2: out = Q * (SCALE2 * sum_s Mpart) ----------------
__global__ __launch_bounds__(256) void qm_kernel(const float* __restrict__ Q,
                                                 const float* __restrict__ Mpart,
                                                 float* __restrict__ Out) {
    __shared__ float M[1024];
    const int blk = blockIdx.x;              // 512 = 128 * 4
    const int p   = blk >> 2;
    const int c   = blk & 3;                 // quarter of the 784 position-pairs
    const int tid = threadIdx.x;

    // ---- sum the 28 partials; fold in the scale
    const float* mp = Mpart + (size_t)p * SPLIT * 1024 + tid * 4;
    v2f s0 = {0.f, 0.f}, s1 = {0.f, 0.f};
    #pragma unroll 7
    for (int s = 0; s < SPLIT; ++s) {
        const float4 v = *(const float4*)&mp[s * 1024];
        const v2f vlo = {v.x, v.y};
        const v2f vhi = {v.z, v.w};
        s0 += vlo; s1 += vhi;
    }
    float4 sum;
    sum.x = s0.x * SCALE2; sum.y = s0.y * SCALE2;
    sum.z = s1.x * SCALE2; sum.w = s1.y * SCALE2;
    *(float4*)&M[tid * 4] = sum;
    __syncthreads();

    const int head = p & 7;
    const int win  = (p >> 3) & 1;
    const int b    = (p >> 4) & 1;
    const int t    = p >> 5;

    if (tid < 196) {
        const int pr = c * 196 + tid;        // position-pair 0..783
        const int y  = pr / 14;
        const int x  = (pr - y * 14) * 2;
        const size_t base = (size_t)((t * 2 + b) * 256 + head * 32) * HW
                          + y * WDIM + win * 28 + x;
        const float* __restrict__ Qb = Q + base;
        float* __restrict__ Ob = Out + base;

        v2f acc[32] = {};                    // 64 VGPRs, one v2f per out channel
        #pragma unroll 8
        for (int dd = 0; dd < 32; ++dd) {
            const v2f qq = *(const v2f*)&Qb[(size_t)dd * HW];   // float2 load
            #pragma unroll
            for (int g4 = 0; g4 < 8; ++g4) {
                const float4 m = *(const float4*)&M[dd * 32 + g4 * 4];  // broadcast
                acc[g4 * 4 + 0] += qq * m.x;
                acc[g4 * 4 + 1] += qq * m.y;
                acc[g4 * 4 + 2] += qq * m.z;
                acc[g4 * 4 + 3] += qq * m.w;
            }
        }
        #pragma unroll
        for (int de = 0; de < 32; ++de)
            *(v2f*)&Ob[(size_t)de * HW] = acc[de];
    }
}

extern "C" void kernel_launch(void* const* d_in, const int* in_sizes, int n_in,
                              void* d_out, int out_size, void* d_ws, size_t ws_size,
                              hipStream_t stream) {
    const float* q = (const float*)d_in[0];
    const float* k = (const float*)d_in[1];
    const float* v = (const float*)d_in[2];
    // d_in[3] is v_lamda == 1 (ignored)
    float* out   = (float*)d_out;
    float* Mpart = (float*)d_ws;   // 128*28*1024 floats = 14.7 MB, fully written by kv

    kv_kernel<<<128 * SPLIT, 256, 0, stream>>>(k, v, Mpart);
    qm_kernel<<<128 * 4, 256, 0, stream>>>(q, Mpart, out);
}